// Round 19
// baseline (515.567 us; speedup 1.0000x reference)
//
#include <hip/hip_runtime.h>
#include <hip/hip_bf16.h>
#include <math.h>

// ---- problem constants ----
#define S_LEN   2048
#define HIDDIM  2048
#define NKH     16
#define NVH     32
#define DKD     128
#define DVD     128
#define CCH     64          // chunk
#define NCHK    32          // S/chunk
#define KEY_DIM 2048
#define VAL_DIM 4096
#define CONV_DIM 8192

#define PA_LDS_BYTES (16384 + 16384 + 32768 + 4096 + 4096 + 256 + 256 + 256)
#define PB_LDS_BYTES ((2 * 29696 + 2048 + 1024 + 1024) * 2 + 2048 * 4)  // 135168
// gemm256: 3 bufs x (B 256x32) bf16 = 3 x 8192 ushorts = 48 KB (A from L2)
#define G256_LDS_BYTES (3 * 8192 * 2)
// gemm128: 3 bufs x (A 128x32 + B 128x32) = 3 x 8192 ushorts = 48 KB
#define G128_LDS_BYTES (3 * 8192 * 2)

typedef __bf16 bf16x8 __attribute__((ext_vector_type(8)));
typedef float f32x4 __attribute__((ext_vector_type(4)));

__device__ __forceinline__ float sigmoid_f(float x) { return 1.f / (1.f + __expf(-x)); }
__device__ __forceinline__ float silu_f(float x) { return x * sigmoid_f(x); }
__device__ __forceinline__ ushort f2bf(float f) {
    unsigned u = __float_as_uint(f);
    u += 0x7fffu + ((u >> 16) & 1u);          // RNE (inputs finite)
    return (ushort)(u >> 16);
}
__device__ __forceinline__ float bf2f(ushort u) {
    return __uint_as_float((unsigned)u << 16);
}

#define GLL(srcp, dstp) __builtin_amdgcn_global_load_lds( \
    (const __attribute__((address_space(1))) void*)(srcp), \
    (__attribute__((address_space(3))) void*)(dstp), 16, 0, 0)

// == merged fp32->bf16 cast: x, W_qkv|W_z, W_out, W_ab-padded (one launch) ===
#define NX8  (S_LEN * HIDDIM / 8)                    // 524288
#define NQ8  (CONV_DIM * HIDDIM / 8)                 // 2097152
#define NZ8  (VAL_DIM * HIDDIM / 8)                  // 1048576
#define NW8  (HIDDIM * VAL_DIM / 8)                  // 1048576
#define NA8  (256 * HIDDIM / 8)                      // 65536
__global__ __launch_bounds__(256) void cast5_kernel(
    const float* __restrict__ x, const float* __restrict__ Wq,
    const float* __restrict__ Wz, const float* __restrict__ Wo,
    const float* __restrict__ Wa, const float* __restrict__ Wb,
    ushort* __restrict__ xb, ushort* __restrict__ wqz, ushort* __restrict__ wob,
    ushort* __restrict__ wab)
{
    int t = blockIdx.x * 256 + threadIdx.x;
    const float* src;
    ushort* dst;
    if (t < NX8) { src = x + (size_t)t * 8; dst = xb + (size_t)t * 8; }
    else if (t < NX8 + NQ8) {
        size_t o = (size_t)(t - NX8) * 8;
        src = Wq + o; dst = wqz + o;
    } else if (t < NX8 + NQ8 + NZ8) {
        size_t o = (size_t)(t - NX8 - NQ8) * 8;
        src = Wz + o; dst = wqz + (size_t)NQ8 * 8 + o;
    } else if (t < NX8 + NQ8 + NZ8 + NW8) {
        size_t o = (size_t)(t - NX8 - NQ8 - NZ8) * 8;
        src = Wo + o; dst = wob + o;
    } else {
        int g = t - NX8 - NQ8 - NZ8 - NW8;           // 0..65535
        int row = g >> 8;
        int c8 = (g & 255) * 8;
        dst = wab + (size_t)g * 8;
        if (row >= 64) {
            uint4 z = {0, 0, 0, 0};
            *(uint4*)dst = z;
            return;
        }
        src = (row < 32) ? (Wa + (size_t)row * HIDDIM + c8)
                         : (Wb + (size_t)(row - 32) * HIDDIM + c8);
    }
    float4 v0 = *(const float4*)(src);
    float4 v1 = *(const float4*)(src + 4);
    union { ushort u[8]; uint4 v; } r;
    r.u[0] = f2bf(v0.x); r.u[1] = f2bf(v0.y); r.u[2] = f2bf(v0.z); r.u[3] = f2bf(v0.w);
    r.u[4] = f2bf(v1.x); r.u[5] = f2bf(v1.y); r.u[6] = f2bf(v1.z); r.u[7] = f2bf(v1.w);
    *(uint4*)dst = r.v;
}

// ==== 256x256 bf16 GEMM, 64x128 wave tile, A-from-L2 + B 3-buf GLL ==========
// 512 thr = 8 waves (4M x 2N), acc[4][8]. A fragments loaded per-tile from
// global (A = 8 MB, L2-hot; cuts per-CU LDS reads 96->64 per tile). B staged
// via 3-buf counted-vmcnt GLL. Grid (49, 8) = 392, XCD-chunked swizzle.
// 3-way epilogue: cols < NS1 -> C0 bf16, < NS2 -> C1 bf16, else C2 f32.
__global__ __launch_bounds__(512, 1) void gemm256_kernel(
    const ushort* __restrict__ A, const ushort* __restrict__ B,
    ushort* __restrict__ C0, ushort* __restrict__ C1, float* __restrict__ C2,
    int K, int NS1, int NS2, int ldc0, int ldc1, int ldc2)
{
    extern __shared__ ushort g2s[];          // [3][B 8192] ushorts
    const int tid = threadIdx.x;
    const int wv = tid >> 6, ln = tid & 63;
    const int wm = wv >> 1, wn = wv & 1;
    const int lrow = ln & 15, lkg = ln >> 4;
    // XCD-chunked swizzle over 392 blocks (392 % 8 == 0)
    const int bid = blockIdx.y * 49 + blockIdx.x;
    const int swz = (bid & 7) * 49 + (bid >> 3);
    const int bm = (swz / 49) * 256, bn = (swz % 49) * 256;

    // B staging: granule g -> frag=g>>6, l=g&63 -> elem (frag*16+(l&15), (l>>4)*8)
    int soff[2];
#pragma unroll
    for (int j = 0; j < 2; ++j) {
        int g = tid + j * 512;
        int l = g & 63;
        soff[j] = (((g >> 6) * 16) + (l & 15)) * K + (l >> 4) * 8;
    }
    const ushort* Bbase = B + (size_t)bn * K;
    // per-lane A fragment pointers (row = bm + wm*64 + mf*16 + lrow, col lkg*8)
    const ushort* Alane = A + (size_t)(bm + wm * 64 + lrow) * K + lkg * 8;

    f32x4 acc[4][8];
#pragma unroll
    for (int m = 0; m < 4; ++m)
#pragma unroll
        for (int n = 0; n < 8; ++n) {
            f32x4 z = {0.f, 0.f, 0.f, 0.f};
            acc[m][n] = z;
        }

#define G256_STAGE(bb, k0) do {                                            \
        ushort* bufB_ = g2s + (bb) * 8192;                                 \
        _Pragma("unroll")                                                  \
        for (int j_ = 0; j_ < 2; ++j_)                                     \
            GLL(Bbase + soff[j_] + (k0), bufB_ + (j_ * 512 + wv * 64) * 8);\
    } while (0)

    const int T = K >> 5;
    // prologue: B(0), B(1) staged; drain B(0) (keep B(1) in flight)
    G256_STAGE(0, 0);
    G256_STAGE(1, 32);
    asm volatile("s_waitcnt vmcnt(2)" ::: "memory");
    __builtin_amdgcn_s_barrier();
    int bb = 0;
    for (int t = 0; t < T; ++t) {
        const ushort* LB = g2s + bb * 8192;
        // read B(t) fragments (landed: drained last iter + barrier)
        bf16x8 bfv[8];
#pragma unroll
        for (int nf = 0; nf < 8; ++nf)
            bfv[nf] = *(const bf16x8*)&LB[((wn * 8 + nf) * 64 + ln) * 8];
        // issue A(t) register loads (L2-hot)
        bf16x8 afv[4];
#pragma unroll
        for (int mf = 0; mf < 4; ++mf)
            afv[mf] = *(const bf16x8*)(Alane + (size_t)(mf * 16) * K + t * 32);
        // stage B(t+2)
        if (t + 2 < T) G256_STAGE((bb >= 1) ? (bb - 1) : (bb + 2), (t + 2) * 32);
        // drain A(t) + B(t+1); keep 2 newest (B(t+2)) in flight
        if (t + 2 < T) {
            asm volatile("s_waitcnt vmcnt(2)" ::: "memory");
        } else {
            asm volatile("s_waitcnt vmcnt(0)" ::: "memory");
        }
        __builtin_amdgcn_s_setprio(1);
#pragma unroll
        for (int mf = 0; mf < 4; ++mf)
#pragma unroll
            for (int nf = 0; nf < 8; ++nf)
                acc[mf][nf] = __builtin_amdgcn_mfma_f32_16x16x32_bf16(
                    afv[mf], bfv[nf], acc[mf][nf], 0, 0, 0);
        __builtin_amdgcn_s_setprio(0);
        __builtin_amdgcn_s_barrier();    // B(t) reads done; B(t+2) may land after
        bb = (bb == 2) ? 0 : bb + 1;
    }
#undef G256_STAGE

    if (bn < NS2) {   // bf16 outputs (whole block on one side; NS1,NS2 %256==0)
        const bool inC1 = (bn >= NS1);
        ushort* Cp = inC1 ? C1 : C0;
        const int ldc = inC1 ? ldc1 : ldc0;
        const int cboff = bn + wn * 128 - (inC1 ? NS1 : 0);
#pragma unroll
        for (int mf = 0; mf < 4; ++mf) {
            const int row0 = bm + wm * 64 + mf * 16 + lkg * 4;
#pragma unroll
            for (int nf = 0; nf < 8; ++nf) {
                ushort* cp = Cp + (size_t)row0 * ldc + cboff + nf * 16 + lrow;
#pragma unroll
                for (int j = 0; j < 4; ++j) cp[(size_t)j * ldc] = f2bf(acc[mf][nf][j]);
            }
        }
    } else {          // f32 ab output
        const int cboff = bn + wn * 128 - NS2;
#pragma unroll
        for (int mf = 0; mf < 4; ++mf) {
            const int row0 = bm + wm * 64 + mf * 16 + lkg * 4;
#pragma unroll
            for (int nf = 0; nf < 8; ++nf) {
                float* cp = C2 + (size_t)row0 * ldc2 + cboff + nf * 16 + lrow;
#pragma unroll
                for (int j = 0; j < 4; ++j) cp[(size_t)j * ldc2] = acc[mf][nf][j];
            }
        }
    }
}

// ======== 128x128 triple-buffered counted-vmcnt bf16 GEMM (BK=32) ===========
__global__ __launch_bounds__(256, 2) void gemm128_kernel(
    const ushort* __restrict__ A, const ushort* __restrict__ B,
    float* __restrict__ C, int N, int K)
{
    extern __shared__ ushort g1s[];          // [3][A 4096 | B 4096] ushorts
    const int tid = threadIdx.x;
    const int wv = tid >> 6, ln = tid & 63;
    const int wm = wv >> 1, wn = wv & 1;
    const int lrow = ln & 15, lkg = ln >> 4;
    const int bm = blockIdx.y * 128, bn = blockIdx.x * 128;

    int soff[2];
#pragma unroll
    for (int j = 0; j < 2; ++j) {
        int g = tid + j * 256;
        int l = g & 63;
        soff[j] = (((g >> 6) * 16) + (l & 15)) * K + (l >> 4) * 8;
    }
    const ushort* Abase = A + (size_t)bm * K;
    const ushort* Bbase = B + (size_t)bn * K;

    f32x4 acc[4][4];
#pragma unroll
    for (int m = 0; m < 4; ++m)
#pragma unroll
        for (int n = 0; n < 4; ++n) {
            f32x4 z = {0.f, 0.f, 0.f, 0.f};
            acc[m][n] = z;
        }

#define G128_STAGE(bb, k0) do {                                            \
        ushort* bufA_ = g1s + (bb) * 8192;                                 \
        ushort* bufB_ = bufA_ + 4096;                                      \
        _Pragma("unroll")                                                  \
        for (int j_ = 0; j_ < 2; ++j_) {                                   \
            GLL(Abase + soff[j_] + (k0), bufA_ + (j_ * 256 + wv * 64) * 8);\
            GLL(Bbase + soff[j_] + (k0), bufB_ + (j_ * 256 + wv * 64) * 8);\
        }                                                                  \
    } while (0)

    const int T = K >> 5;
    G128_STAGE(0, 0);
    G128_STAGE(1, 32);
    int bb = 0;
    for (int t = 0; t < T; ++t) {
        if (t + 1 < T) {
            asm volatile("s_waitcnt vmcnt(4)" ::: "memory");
        } else {
            asm volatile("s_waitcnt vmcnt(0)" ::: "memory");
        }
        __builtin_amdgcn_s_barrier();
        if (t + 2 < T) G128_STAGE((bb >= 1) ? (bb - 1) : (bb + 2), (t + 2) * 32);
        const ushort* LA = g1s + bb * 8192;
        const ushort* LB = LA + 4096;
        __builtin_amdgcn_s_setprio(1);
        {
            bf16x8 afv[4], bfv[4];
#pragma unroll
            for (int mf = 0; mf < 4; ++mf)
                afv[mf] = *(const bf16x8*)&LA[((wm * 4 + mf) * 64 + ln) * 8];
#pragma unroll
            for (int nf = 0; nf < 4; ++nf)
                bfv[nf] = *(const bf16x8*)&LB[((wn * 4 + nf) * 64 + ln) * 8];
#pragma unroll
            for (int mf = 0; mf < 4; ++mf)
#pragma unroll
                for (int nf = 0; nf < 4; ++nf)
                    acc[mf][nf] = __builtin_amdgcn_mfma_f32_16x16x32_bf16(
                        afv[mf], bfv[nf], acc[mf][nf], 0, 0, 0);
        }
        __builtin_amdgcn_s_setprio(0);
        bb = (bb == 2) ? 0 : bb + 1;
    }
#undef G128_STAGE

#pragma unroll
    for (int mf = 0; mf < 4; ++mf) {
        const int row0 = bm + wm * 64 + mf * 16 + lkg * 4;
#pragma unroll
        for (int nf = 0; nf < 4; ++nf) {
            float* cp = C + (size_t)row0 * N + bn + wn * 64 + nf * 16 + lrow;
#pragma unroll
            for (int j = 0; j < 4; ++j) cp[(size_t)j * N] = acc[mf][nf][j];
        }
    }
}

// ===== fused front: conv1d(K=4)+SiLU + q/k L2norm + v split, 1 block/row ====
__global__ __launch_bounds__(256) void front_kernel(
    const ushort* __restrict__ pre, const float* __restrict__ cw,
    ushort* __restrict__ qnb, ushort* __restrict__ knb, ushort* __restrict__ vbuf)
{
    __shared__ float stage[4096];
    __shared__ float sums[32];
    __shared__ float scal[32];
    const int s = blockIdx.x;
    const int tid = threadIdx.x;

#pragma unroll
    for (int cg = 0; cg < 8; ++cg) {
        const int c = cg * 1024 + tid * 4;
        float w[4][4];
#pragma unroll
        for (int j = 0; j < 4; ++j) {
            float4 wj = *(const float4*)(cw + (size_t)(c + j) * 4);
            w[j][0] = wj.x; w[j][1] = wj.y; w[j][2] = wj.z; w[j][3] = wj.w;
        }
        float a0 = 0.f, a1 = 0.f, a2 = 0.f, a3 = 0.f;
#pragma unroll
        for (int t = 0; t < 4; ++t) {
            int ss = s - 3 + t;
            if (ss >= 0) {
                uint2 xv = *(const uint2*)(pre + (size_t)ss * CONV_DIM + c);
                a0 = fmaf(bf2f((ushort)xv.x), w[0][t], a0);
                a1 = fmaf(bf2f((ushort)(xv.x >> 16)), w[1][t], a1);
                a2 = fmaf(bf2f((ushort)xv.y), w[2][t], a2);
                a3 = fmaf(bf2f((ushort)(xv.y >> 16)), w[3][t], a3);
            }
        }
        a0 = silu_f(a0); a1 = silu_f(a1); a2 = silu_f(a2); a3 = silu_f(a3);
        if (cg < 4) {
            float4 v4 = make_float4(a0, a1, a2, a3);
            *(float4*)&stage[c] = v4;
            float ss2 = a0 * a0 + a1 * a1 + a2 * a2 + a3 * a3;
#pragma unroll
            for (int m = 1; m < 32; m <<= 1) ss2 += __shfl_xor(ss2, m, 32);
            if ((tid & 31) == 0) sums[c >> 7] = ss2;
        } else {
            union { ushort u2[4]; uint2 v; } p;
            p.u2[0] = f2bf(a0); p.u2[1] = f2bf(a1);
            p.u2[2] = f2bf(a2); p.u2[3] = f2bf(a3);
            *(uint2*)(vbuf + (size_t)s * VAL_DIM + (c - 4096)) = p.v;
        }
    }
    __syncthreads();
    if (tid < 32) {
        float sc = rsqrtf(sums[tid] + 1e-6f);
        if (tid < 16) sc *= 0.08838834764831843f;     // q: DK^-0.5
        scal[tid] = sc;
    }
    __syncthreads();
#pragma unroll
    for (int j = 0; j < 4; ++j) {
        const int c = j * 1024 + tid * 4;
        float4 v4 = *(const float4*)&stage[c];
        const float sc = scal[c >> 7];
        union { ushort u2[4]; uint2 v; } p;
        p.u2[0] = f2bf(v4.x * sc); p.u2[1] = f2bf(v4.y * sc);
        p.u2[2] = f2bf(v4.z * sc); p.u2[3] = f2bf(v4.w * sc);
        if (c < 2048)
            *(uint2*)(qnb + ((size_t)(s * NKH + (c >> 7))) * DKD + (c & 127)) = p.v;
        else
            *(uint2*)(knb + ((size_t)(s * NKH + ((c >> 7) - 16))) * DKD + (c & 127)) = p.v;
    }
}

// ================= Phase A: per (head, chunk) intra-chunk work ==============
// gb fused: computes g = -exp(A_log)*softplus(a+dt_bias), beta = sigmoid(b)
// from ab_buf [S][256] directly. outputs: u bf16, kcd bf16, scores bf16,
// gcs f32, knT bf16 (even h only).
__global__ __launch_bounds__(256) void phaseA_kernel(
    const ushort* __restrict__ qnb, const ushort* __restrict__ knb,
    const ushort* __restrict__ vbuf, const float* __restrict__ ab,
    const float* __restrict__ dt_bias, const float* __restrict__ A_log,
    ushort* __restrict__ u, ushort* __restrict__ kcd,
    ushort* __restrict__ scores, float* __restrict__ gcs_out,
    ushort* __restrict__ knT)
{
    extern __shared__ char pasm[];
    ushort* kb    = (ushort*)(pasm);            // 16KB frag [m4][ks4][64][8]
    ushort* qb    = (ushort*)(pasm + 16384);    // 16KB frag; later P f32[16][256]
    ushort* Xb    = (ushort*)(pasm + 32768);    // 32KB [t2(2)][ct(16)][64][8]
    float*  Adiag = (float*)(pasm + 65536);     // 4KB
    ushort* Ab    = (ushort*)(pasm + 69632);    // 4KB
    float*  gcs_s = (float*)(pasm + 73728);
    float*  bet_s = (float*)(pasm + 73984);
    float*  scK_s = (float*)(pasm + 74240);
    float*  Pf    = (float*)qb;

    const int n = blockIdx.x, h = blockIdx.y, kh = h >> 1;
    const int tid = threadIdx.x;
    const int s0 = n * CCH;
    const int wv = tid >> 6, ln = tid & 63;
    const int lrow = ln & 15, lkg = ln >> 4;

    float xr[64];
    if (tid < 128) {
        const ushort* vp = vbuf + (size_t)s0 * VAL_DIM + h * DVD + tid;
#pragma unroll
        for (int i = 0; i < 64; ++i) xr[i] = bf2f(vp[(size_t)i * VAL_DIM]);
    } else {
        const ushort* kp = knb + ((size_t)s0 * NKH + kh) * DKD + (tid - 128);
#pragma unroll
        for (int i = 0; i < 64; ++i) xr[i] = bf2f(kp[(size_t)i * (NKH * DKD)]);
    }

    {
        uint4 z = {0, 0, 0, 0};
#pragma unroll
        for (int i = 0; i < 8; ++i)
            *(uint4*)&Xb[(i * 256 + tid) * 8] = z;
        *(uint4*)&Ab[tid * 8] = z;
    }

    if (tid < 64) {
        // fused gb: g from softplus, beta from sigmoid (ab stride 256)
        float av = ab[(size_t)(s0 + tid) * 256 + h] + dt_bias[h];
        float sp = (av > 20.f) ? av : log1pf(__expf(av));
        float gv = -__expf(A_log[h]) * sp;
#pragma unroll
        for (int off = 1; off < 64; off <<= 1) {
            float pv = __shfl_up(gv, off, 64);
            if (tid >= off) gv += pv;
        }
        float bv = sigmoid_f(ab[(size_t)(s0 + tid) * 256 + 32 + h]);
        gcs_s[tid] = gv;
        bet_s[tid] = bv;
        scK_s[tid] = bv * __expf(gv);
        gcs_out[(size_t)h * S_LEN + s0 + tid] = gv;
    }

    {   // stage k and q (both bf16 -> straight uint4 copies)
        const int r = tid >> 2, c0 = (tid & 3) * 32;
        const int mbase = (((r >> 4) * 4 + (tid & 3)) * 64 + (r & 15)) * 8;
        const ushort* ksrc = knb + ((size_t)(s0 + r) * NKH + kh) * DKD + c0;
        const ushort* qsrc = qnb + ((size_t)(s0 + r) * NKH + kh) * DKD + c0;
#pragma unroll
        for (int j0 = 0; j0 < 4; ++j0) {
            *(uint4*)&kb[mbase + (j0 << 7)] = *(const uint4*)(ksrc + j0 * 8);
            *(uint4*)&qb[mbase + (j0 << 7)] = *(const uint4*)(qsrc + j0 * 8);
        }
    }
    __syncthreads();    // B1

    f32x4 accA[4], accQ[4];
#pragma unroll
    for (int j = 0; j < 4; ++j) {
        f32x4 z = {0.f, 0.f, 0.f, 0.f};
        accA[j] = z; accQ[j] = z;
    }
#pragma unroll
    for (int ks = 0; ks < 4; ++ks) {
        bf16x8 a_k = *(const bf16x8*)&kb[((wv * 4 + ks) * 64 + ln) * 8];
        bf16x8 a_q = *(const bf16x8*)&qb[((wv * 4 + ks) * 64 + ln) * 8];
#pragma unroll
        for (int j = 0; j < 4; ++j) {
            bf16x8 b_k = *(const bf16x8*)&kb[((j * 4 + ks) * 64 + ln) * 8];
            accA[j] = __builtin_amdgcn_mfma_f32_16x16x32_bf16(a_k, b_k, accA[j], 0, 0, 0);
            accQ[j] = __builtin_amdgcn_mfma_f32_16x16x32_bf16(a_q, b_k, accQ[j], 0, 0, 0);
        }
    }
    {
        ushort* scp = scores + (size_t)(h * NCHK + n) * (CCH * CCH);
#pragma unroll
        for (int j = 0; j < 4; ++j) {
            const int c = j * 16 + lrow;
            const float gc = gcs_s[c];
#pragma unroll
            for (int jj = 0; jj < 4; ++jj) {
                const int i = wv * 16 + lkg * 4 + jj;
                const float e = __expf(gcs_s[i] - gc);
                float sv = (i >= c) ? (accQ[j][jj] * e) : 0.f;
                scp[i * CCH + c] = f2bf(sv);
                float aval = (i > c) ? (-bet_s[i] * accA[j][jj] * e) : 0.f;
                if (j == wv) {
                    Adiag[wv * 256 + (i & 15) * 16 + lrow] = aval;
                } else if (j < wv) {
                    const int f = (wv == 1) ? 0 : ((wv == 2) ? 1 : (2 + (j >> 1)));
                    const int lk = ((j & 1) << 4) | lrow;
                    const int lane2 = (i & 15) | ((lk >> 3) << 4);
                    Ab[(f * 64 + lane2) * 8 + (lk & 7)] = f2bf(aval);
                }
            }
        }
    }
    if (tid < 128) {
#pragma unroll
        for (int i4 = 0; i4 < 16; ++i4) {
            float4 b4 = *(const float4*)&bet_s[i4 * 4];
            xr[i4 * 4 + 0] *= b4.x; xr[i4 * 4 + 1] *= b4.y;
            xr[i4 * 4 + 2] *= b4.z; xr[i4 * 4 + 3] *= b4.w;
        }
    } else {
#pragma unroll
        for (int i4 = 0; i4 < 16; ++i4) {
            float4 b4 = *(const float4*)&scK_s[i4 * 4];
            xr[i4 * 4 + 0] *= b4.x; xr[i4 * 4 + 1] *= b4.y;
            xr[i4 * 4 + 2] *= b4.z; xr[i4 * 4 + 3] *= b4.w;
        }
    }
    __syncthreads();    // B2

    const int ct = tid >> 4, lct = tid & 15;
#pragma unroll
    for (int s = 0; s < 4; ++s) {
        float y[16];
        float pr[16];
        if (s > 0) {
#pragma unroll
            for (int r = 0; r < 16; ++r) pr[r] = Pf[r * 256 + tid];
        } else {
#pragma unroll
            for (int r = 0; r < 16; ++r) pr[r] = 0.f;
        }
#pragma unroll
        for (int r = 0; r < 16; ++r) {
            float acc = xr[s * 16 + r] + pr[r];
#pragma unroll
            for (int k4 = 0; k4 < 16; k4 += 4) {
                if (k4 < r) {
                    float4 a4 = *(const float4*)&Adiag[s * 256 + r * 16 + k4];
                    if (k4 + 0 < r) acc = fmaf(a4.x, y[k4 + 0], acc);
                    if (k4 + 1 < r) acc = fmaf(a4.y, y[k4 + 1], acc);
                    if (k4 + 2 < r) acc = fmaf(a4.z, y[k4 + 2], acc);
                    if (k4 + 3 < r) acc = fmaf(a4.w, y[k4 + 3], acc);
                }
            }
            y[r] = acc;
        }
        if (tid < 128) {
            ushort* up = u + (size_t)(h * NCHK + n) * (CCH * DVD) + (s * 16) * DVD + tid;
#pragma unroll
            for (int r = 0; r < 16; ++r) up[r * DVD] = f2bf(y[r]);
        } else {
            ushort* kp = kcd + (size_t)(h * NCHK + n) * (CCH * DKD) + (s * 16) * DKD + (tid - 128);
#pragma unroll
            for (int r = 0; r < 16; ++r) kp[r * DKD] = f2bf(y[r]);
        }
        if (s < 3) {
#pragma unroll
            for (int half = 0; half < 2; ++half) {
                union { ushort us[8]; uint4 v; } p;
#pragma unroll
                for (int e = 0; e < 8; ++e) p.us[e] = f2bf(y[half * 8 + e]);
                const int kg = (s & 1) * 2 + half;
                *(uint4*)&Xb[(((s >> 1) * 16 + ct) * 64 + (kg * 16 + lct)) * 8] = p.v;
            }
            __syncthreads();
            const int snx = s + 1;
            const int nT2 = (snx + 1) >> 1;
            f32x4 accP[4];
#pragma unroll
            for (int ctl = 0; ctl < 4; ++ctl) {
                f32x4 z = {0.f, 0.f, 0.f, 0.f};
                accP[ctl] = z;
            }
#pragma unroll
            for (int t2 = 0; t2 < 2; ++t2) {
                if (t2 < nT2) {
                    const int f = (snx == 1) ? 0 : ((snx == 2) ? 1 : (2 + t2));
                    bf16x8 a = *(const bf16x8*)&Ab[(f * 64 + ln) * 8];
#pragma unroll
                    for (int ctl = 0; ctl < 4; ++ctl) {
                        bf16x8 b = *(const bf16x8*)&Xb[((t2 * 16 + wv * 4 + ctl) * 64 + ln) * 8];
                        accP[ctl] = __builtin_amdgcn_mfma_f32_16x16x32_bf16(a, b, accP[ctl], 0, 0, 0);
                    }
                }
            }
#pragma unroll
            for (int ctl = 0; ctl < 4; ++ctl)
#pragma unroll
                for (int jj = 0; jj < 4; ++jj)
                    Pf[(lkg * 4 + jj) * 256 + wv * 64 + ctl * 16 + lrow] = accP[ctl][jj];
            __syncthreads();
        }
    }

    if (!(h & 1)) {
        const int dk = tid >> 1, ch = (tid & 1) * 32;
        ushort* dst = knT + ((size_t)(kh * NCHK + n) * DKD + dk) * CCH + ch;
        const int kpart = ((dk >> 5) * 64) * 8 + (((dk >> 3) & 3) << 4) * 8 + (dk & 7);
#pragma unroll
        for (int j0 = 0; j0 < 32; j0 += 8) {
            union { ushort us[8]; uint4 v; } p;
#pragma unroll
            for (int j = 0; j < 8; ++j) {
                const int row = ch + j0 + j;
                p.us[j] = kb[((row >> 4) * 4 * 64 + (row & 15)) * 8 + kpart];
            }
            *(uint4*)(dst + j0) = p.v;
        }
    }
}

// ====== Phase B: inter-chunk state scan (MFMA), prefetch-pipelined ==========
__global__ __launch_bounds__(256) void phaseB_kernel(
    const ushort* __restrict__ qnb, const ushort* __restrict__ knT,
    const ushort* __restrict__ u, const ushort* __restrict__ kcd,
    const ushort* __restrict__ sc, const float* __restrict__ gcs,
    ushort* __restrict__ obuf)
{
    extern __shared__ ushort smu[];
    // stage buf b at b*29696: {q 8192, kc 8192, sc 4096, kT 8192, u 1024}
    ushort* storg  = smu + 59392;    // 2048  S^T bf16
    ushort* vnorg  = smu + 61440;    // 1024
    ushort* vnsorg = smu + 62464;    // 1024
    float*  gcsall = (float*)(smu + 63488);  // 2048 floats (8 KB)

    const int h = blockIdx.x;
    const int dvb = blockIdx.y;
    const int d0 = dvb * 16;
    const int kh = h >> 1;
    const int tid = threadIdx.x;
    const int wv = tid >> 6, ln = tid & 63;
    const int lrow = ln & 15, lkg = ln >> 4;

    {   // zero S^T
        uint4 z = {0, 0, 0, 0};
        *(uint4*)&storg[tid * 8] = z;
    }

    const int q_lane  = lrow * (NKH * DKD) + kh * DKD + wv * 32 + lkg * 8;
    const int kc_lane = lrow * DKD + wv * 32 + lkg * 8;
    const int st_lane = ((tid >> 7) * 16 + lrow) * 64 + ((tid >> 6) & 1) * 32 + lkg * 8;
    const int dst_e   = wv * 512;

#define PBSTG(bsel, nn) do {                                                  \
        const ushort* qsrc_  = qnb + (size_t)((nn) * CCH) * (NKH * DKD);      \
        const ushort* kcsrc_ = kcd + (size_t)(h * NCHK + (nn)) * (CCH * DKD); \
        const ushort* scsrc_ = sc  + (size_t)(h * NCHK + (nn)) * (CCH * CCH); \
        const ushort* kTsrc_ = knT + (size_t)(kh * NCHK + (nn)) * (DKD * CCH);\
        const ushort* usrc_  = u   + (size_t)(h * NCHK + (nn)) * (CCH * DVD) + d0; \
        ushort* base_ = smu + (bsel) * 29696;                                 \
        _Pragma("unroll")                                                     \
        for (int r_ = 0; r_ < 4; ++r_) {                                      \
            GLL(qsrc_ + q_lane + r_ * 32768, base_ + r_ * 2048 + dst_e);      \
            GLL(kcsrc_ + kc_lane + r_ * 2048, base_ + 8192 + r_ * 2048 + dst_e); \
            GLL(kTsrc_ + st_lane + r_ * 2048, base_ + 20480 + r_ * 2048 + dst_e); \
        }                                                                     \
        _Pragma("unroll")                                                     \
        for (int r_ = 0; r_ < 2; ++r_)                                        \
            GLL(scsrc_ + st_lane + r_ * 2048, base_ + 16384 + r_ * 2048 + dst_e); \
        if (tid < 128)                                                        \
            GLL(usrc_ + (tid >> 1) * DVD + (tid & 1) * 8, base_ + 28672 + tid * 8); \
    } while (0)

    PBSTG(0, 0);
    {
        float4 g0 = *(const float4*)(gcs + (size_t)h * S_LEN + tid * 8);
        float4 g1 = *(const float4*)(gcs + (size_t)h * S_LEN + tid * 8 + 4);
        *(float4*)&gcsall[tid * 8] = g0;
        *(float4*)&gcsall[tid * 8 + 4] = g1;
    }
    __syncthreads();

    f32x4 accS0 = {0.f, 0.f, 0.f, 0.f}, accS1 = {0.f, 0.f, 0.f, 0.f};

    for (int n = 0; n < NCHK; ++n) {
        const int cur = n & 1;
        if (n + 1 < NCHK) PBSTG(cur ^ 1, n + 1);
        const ushort* qorg  = smu + cur * 29696;
        const ushort* kcorg = qorg + 8192;
        const ushort* scorg = qorg + 16384;
        const ushort* kTorg = qorg + 20480;
        const ushort* uorg  = qorg + 28672;
        const float*  gcs_s = gcsall + n * 64;
        const int s0 = n * CCH;

        f32x4 accv = {0.f, 0.f, 0.f, 0.f};
        f32x4 acco = {0.f, 0.f, 0.f, 0.f};
#pragma unroll
        for (int ks = 0; ks < 4; ++ks) {
            bf16x8 b_st = *(const bf16x8*)&storg[(ks * 64 + ln) * 8];
            bf16x8 a_kc = *(const bf16x8*)&kcorg[((wv * 4 + ks) * 64 + ln) * 8];
            bf16x8 a_q  = *(const bf16x8*)&qorg[((wv * 4 + ks) * 64 + ln) * 8];
            accv = __builtin_amdgcn_mfma_f32_16x16x32_bf16(a_kc, b_st, accv, 0, 0, 0);
            acco = __builtin_amdgcn_mfma_f32_16x16x32_bf16(a_q, b_st, acco, 0, 0, 0);
        }
        const int row = wv * 16 + lkg * 4;
        float u0 = bf2f(uorg[(row + 0) * 16 + lrow]);
        float u1 = bf2f(uorg[(row + 1) * 16 + lrow]);
        float u2 = bf2f(uorg[(row + 2) * 16 + lrow]);
        float u3 = bf2f(uorg[(row + 3) * 16 + lrow]);
        const float gl = gcs_s[63];
        float vn0 = u0 - accv[0], vn1 = u1 - accv[1];
        float vn2 = u2 - accv[2], vn3 = u3 - accv[3];
        {
            float g0 = gcs_s[row], g1 = gcs_s[row + 1], g2 = gcs_s[row + 2], g3 = gcs_s[row + 3];
            acco[0] *= __expf(g0); acco[1] *= __expf(g1);
            acco[2] *= __expf(g2); acco[3] *= __expf(g3);
            const int eb = ((wv >> 1) * 64 + ((wv & 1) * 2 + (lkg >> 1)) * 16 + lrow) * 8
                         + (lkg & 1) * 4;
            union { ushort u2a[4]; uint2 v; } pa, pb;
            pa.u2a[0] = f2bf(vn0); pa.u2a[1] = f2bf(vn1);
            pa.u2a[2] = f2bf(vn2); pa.u2a[3] = f2bf(vn3);
            pb.u2a[0] = f2bf(vn0 * __expf(gl - g0)); pb.u2a[1] = f2bf(vn1 * __expf(gl - g1));
            pb.u2a[2] = f2bf(vn2 * __expf(gl - g2)); pb.u2a[3] = f2bf(vn3 * __expf(gl - g3));
            *(uint2*)&vnorg[eb] = pa.v;
            *(uint2*)&vnsorg[eb] = pb.v;
        }
        __syncthreads();                 // B2: v_new published (+ prefetch drained)

#pragma unroll
        for (int ks = 0; ks < 2; ++ks) {
            bf16x8 a_sc = *(const bf16x8*)&scorg[((wv * 2 + ks) * 64 + ln) * 8];
            bf16x8 b_vn = *(const bf16x8*)&vnorg[(ks * 64 + ln) * 8];
            acco = __builtin_amdgcn_mfma_f32_16x16x32_bf16(a_sc, b_vn, acco, 0, 0, 0);
        }
        ushort* op = obuf + (size_t)(s0 + row) * VAL_DIM + h * DVD + d0 + lrow;
        op[0] = f2bf(acco[0]); op[VAL_DIM] = f2bf(acco[1]);
        op[2 * VAL_DIM] = f2bf(acco[2]); op[3 * VAL_DIM] = f2bf(acco[3]);

        const float egl = __expf(gl);
        accS0 *= egl; accS1 *= egl;
#pragma unroll
        for (int ks = 0; ks < 2; ++ks) {
            bf16x8 a_vs = *(const bf16x8*)&vnsorg[(ks * 64 + ln) * 8];
            bf16x8 b_k0 = *(const bf16x8*)&kTorg[(((wv * 2 + 0) * 2 + ks) * 64 + ln) * 8];
            bf16x8 b_k1 = *(const bf16x8*)&kTorg[(((wv * 2 + 1) * 2 + ks) * 64 + ln) * 8];
            accS0 = __builtin_amdgcn_mfma_f32_16x16x32_bf16(a_vs, b_k0, accS0, 0, 0, 0);
            accS1 = __builtin_amdgcn_mfma_f32_16x16x32_bf16(a_vs, b_k1, accS1, 0, 0, 0);
        }
#pragma unroll
        for (int j = 0; j < 4; ++j) {
            storg[(wv * 64 + ((lrow >> 3)) * 16 + lkg * 4 + j) * 8 + (lrow & 7)] = f2bf(accS0[j]);
            storg[(wv * 64 + (2 + (lrow >> 3)) * 16 + lkg * 4 + j) * 8 + (lrow & 7)] = f2bf(accS1[j]);
        }
        __syncthreads();                 // B3
    }
#undef PBSTG
}

// ============ RMSNorm * norm_w * silu(z) -> bf16 (bf16 o and z) =============
__global__ __launch_bounds__(256) void norm_kernel(
    const ushort* __restrict__ obuf, const ushort* __restrict__ z,
    const float* __restrict__ nw, ushort* __restrict__ hbuf)
{
    int row = (blockIdx.x * 256 + threadIdx.x) >> 6;
    int lane = threadIdx.x & 63;
    uint ov = *(const uint*)(obuf + (size_t)row * DVD + lane * 2);
    float x0 = bf2f((ushort)ov), x1 = bf2f((ushort)(ov >> 16));
    float ss = x0 * x0 + x1 * x1;
#pragma unroll
    for (int m = 1; m < 64; m <<= 1) ss += __shfl_xor(ss, m, 64);
    float scale = rsqrtf(ss * (1.f / DVD) + 1e-6f);
    uint zv = *(const uint*)(z + (size_t)row * DVD + lane * 2);
    float z0 = bf2f((ushort)zv), z1 = bf2f((ushort)(zv >> 16));
    float2 w2 = *(const float2*)(nw + lane * 2);
    float h0 = x0 * scale * w2.x * silu_f(z0);
    float h1 = x1 * scale * w2.y * silu_f(z1);
    union { ushort u[2]; uint v; } r;
    r.u[0] = f2bf(h0); r.u[1] = f2bf(h1);
    *(uint*)(hbuf + (size_t)row * DVD + lane * 2) = r.v;
}

// ============================================================================
extern "C" void kernel_launch(void* const* d_in, const int* in_sizes, int n_in,
                              void* d_out, int out_size, void* d_ws, size_t ws_size,
                              hipStream_t stream)
{
    (void)in_sizes; (void)n_in; (void)out_size; (void)ws_size;
    const float* x      = (const float*)d_in[0];
    const float* W_qkv  = (const float*)d_in[1];
    const float* W_z    = (const float*)d_in[2];
    const float* W_a    = (const float*)d_in[3];
    const float* W_b    = (const float*)d_in[4];
    const float* conv_w = (const float*)d_in[5];
    const float* dt_b   = (const float*)d_in[6];
    const float* A_log  = (const float*)d_in[7];
    const float* norm_w = (const float*)d_in[8];
    const float* W_out  = (const float*)d_in[9];
    float* out = (float*)d_out;

    // ---- workspace layout (bytes), overlaid by liveness; total ~218.9 MB ---
    char* ws = (char*)d_ws;
    // region A @0: mixed_pre bf16 33.5MB (steps 2-4) -> {u bf16, kcd, knT}
    ushort* mixed_pre = (ushort*)(ws);                  // 33,554,432 (bf16)
    ushort* u_buf     = (ushort*)(ws);                  // 16,777,216 (bf16)
    ushort* kcd_buf   = (ushort*)(ws + 33554432);       // 16,777,216
    ushort* knT_buf   = (ushort*)(ws + 50331648);       //  8,388,608
    // region B @67,108,864:
    //   steps 1-2: wqz 50.3MB [.., 117440512) + wab 1MB + xb 8.4MB
    //   step 4-7 : vbuf bf16 16.8MB @67108864
    //   step 8+  : obuf bf16 @83886080 ; hbuf @100663296
    ushort* wqz       = (ushort*)(ws + 67108864);       // 12288x2048 bf16
    ushort* wab       = (ushort*)(ws + 117440512);      //   256x2048 bf16 (1MB)
    ushort* xb        = (ushort*)(ws + 118489088);      //  8,388,608
    ushort* vbuf      = (ushort*)(ws + 67108864);       // 16,777,216 (bf16)
    ushort* obuf      = (ushort*)(ws + 83886080);       // 16,777,216 (bf16)
    ushort* hbuf      = (ushort*)(ws + 100663296);
    // fixed regions
    ushort* z_buf     = (ushort*)(ws + 134217728);      // 16,777,216 (bf16)
    ushort* sc_buf    = (ushort*)(ws + 167772160);      //  8,388,608
    ushort* qnb       = (ushort*)(ws + 176160768);      //  8,388,608
    ushort* knb       = (ushort*)(ws + 184549376);      //  8,388,608 (bf16)
    float*  ab_buf    = (float*)(ws + 192937984);       //  2,097,152 (disjoint!)
    float*  gcs_buf   = (float*)(ws + 201850880);       //    262,144
    ushort* wob       = (ushort*)(ws + 202113024);      // 16,777,216 -> 218.9MB

    hipFuncSetAttribute((const void*)phaseA_kernel,
                        hipFuncAttributeMaxDynamicSharedMemorySize, PA_LDS_BYTES);
    hipFuncSetAttribute((const void*)phaseB_kernel,
                        hipFuncAttributeMaxDynamicSharedMemorySize, PB_LDS_BYTES);
    hipFuncSetAttribute((const void*)gemm256_kernel,
                        hipFuncAttributeMaxDynamicSharedMemorySize, G256_LDS_BYTES);
    hipFuncSetAttribute((const void*)gemm128_kernel,
                        hipFuncAttributeMaxDynamicSharedMemorySize, G128_LDS_BYTES);

    dim3 blk(256);
    // 1) merged casts: x->xb, W_qkv|W_z->wqz, W_out->wob, W_ab->wab (one launch)
    cast5_kernel<<<(NX8 + NQ8 + NZ8 + NW8 + NA8) / 256, blk, 0, stream>>>(
        x, W_qkv, W_z, W_out, W_a, W_b, xb, wqz, wob, wab);
    // 2) fused qkv+z+ab projection (A-from-L2, B 3-buf; XCD-chunk swizzle)
    gemm256_kernel<<<dim3(49, S_LEN / 256), dim3(512), G256_LDS_BYTES, stream>>>(
        xb, wqz, mixed_pre, z_buf, ab_buf, HIDDIM,
        CONV_DIM, CONV_DIM + VAL_DIM, CONV_DIM, VAL_DIM, 256);
    // 4) fused conv+silu+l2norm+v-split (bf16 in/out)
    front_kernel<<<S_LEN, blk, 0, stream>>>(mixed_pre, conv_w, qnb, knb, vbuf);
    // 7) phase A (intra-chunk, blocked-MFMA solve; gb fused; bf16 in/out)
    phaseA_kernel<<<dim3(NCHK, NVH), blk, PA_LDS_BYTES, stream>>>(
        qnb, knb, vbuf, ab_buf, dt_b, A_log, u_buf, kcd_buf, sc_buf, gcs_buf, knT_buf);
    // 8) phase B (inter-chunk scan, MFMA, prefetch-pipelined, bf16 o)
    phaseB_kernel<<<dim3(NVH, 8), blk, PB_LDS_BYTES, stream>>>(
        qnb, knT_buf, u_buf, kcd_buf, sc_buf, gcs_buf, obuf);
    // 9) gated RMSNorm -> bf16
    norm_kernel<<<(S_LEN * NVH * 64) / 256, blk, 0, stream>>>(obuf, z_buf, norm_w, hbuf);
    // 10) output projection (128^2 triple-buffered BK=32, 256 blocks)
    gemm128_kernel<<<dim3(HIDDIM / 128, S_LEN / 128), blk, G128_LDS_BYTES, stream>>>(
        hbuf, wob, out, HIDDIM, VAL_DIM);
}